// Round 2
// baseline (269.728 us; speedup 1.0000x reference)
//
#include <hip/hip_runtime.h>

// out[b,y,x] = sum_c sum_{p,q in [0,4)} feat1[b,c,y+p-2,x+q-2] * feat2[b,c,p,q]
// B=4096, C=512, H=W=4. Memory-bound: 268 MB in, 256 KB out.

__global__ __launch_bounds__(512) void corr_kernel(
        const float* __restrict__ feat1,
        const float* __restrict__ feat2,
        float* __restrict__ out) {
    const int b = blockIdx.x;
    const int c = threadIdx.x;                       // 0..511
    const size_t base = ((size_t)b * 512 + c) * 16;  // 16 floats per (b,c)

    const float4* f1p = reinterpret_cast<const float4*>(feat1 + base);
    const float4* f2p = reinterpret_cast<const float4*>(feat2 + base);

    float f1[16], f2[16];
    #pragma unroll
    for (int i = 0; i < 4; ++i) {
        float4 a = f1p[i];
        f1[4*i+0] = a.x; f1[4*i+1] = a.y; f1[4*i+2] = a.z; f1[4*i+3] = a.w;
        float4 t = f2p[i];
        f2[4*i+0] = t.x; f2[4*i+1] = t.y; f2[4*i+2] = t.z; f2[4*i+3] = t.w;
    }

    float acc[16];
    #pragma unroll
    for (int i = 0; i < 16; ++i) acc[i] = 0.f;

    // 144 compile-time-unrolled FMAs (OOB terms folded away)
    #pragma unroll
    for (int y = 0; y < 4; ++y)
    #pragma unroll
    for (int p = 0; p < 4; ++p) {
        const int u = y + p - 2;
        if (u < 0 || u > 3) continue;
        #pragma unroll
        for (int x = 0; x < 4; ++x)
        #pragma unroll
        for (int q = 0; q < 4; ++q) {
            const int v = x + q - 2;
            if (v < 0 || v > 3) continue;
            acc[y*4 + x] = fmaf(f1[u*4 + v], f2[p*4 + q], acc[y*4 + x]);
        }
    }

    // Reduce 16 components across 64 lanes with a value-splitting butterfly:
    // step k pairs lanes differing in bit k; each lane keeps the half of its
    // components whose index-bit-k matches its own lane-bit-k and receives the
    // partner's matching half. After 4 steps lane l holds component (l & 15)
    // summed over its 16-lane group; two plain xor steps finish the wave.
    const int lane = threadIdx.x & 63;
    float v[16];
    #pragma unroll
    for (int i = 0; i < 16; ++i) v[i] = acc[i];
    #pragma unroll
    for (int k = 0; k < 4; ++k) {
        const int m = 1 << k;
        const int pairs = 8 >> k;
        const bool sel = (lane >> k) & 1;
        float w[8];
        #pragma unroll
        for (int p = 0; p < pairs; ++p) {
            float keep = sel ? v[2*p+1] : v[2*p];
            float send = sel ? v[2*p]   : v[2*p+1];
            float recv = __shfl_xor(send, m, 64);
            w[p] = keep + recv;
        }
        #pragma unroll
        for (int p = 0; p < pairs; ++p) v[p] = w[p];
    }
    float r = v[0];
    r += __shfl_xor(r, 16, 64);
    r += __shfl_xor(r, 32, 64);
    // lane l now holds out-component (l & 15) summed over the whole wave

    __shared__ float red[8][16];
    const int wave = threadIdx.x >> 6;
    if (lane < 16) red[wave][lane] = r;
    __syncthreads();
    if (threadIdx.x < 16) {
        float s = 0.f;
        #pragma unroll
        for (int wv = 0; wv < 8; ++wv) s += red[wv][threadIdx.x];
        out[(size_t)b * 16 + threadIdx.x] = s;
    }
}

extern "C" void kernel_launch(void* const* d_in, const int* in_sizes, int n_in,
                              void* d_out, int out_size, void* d_ws, size_t ws_size,
                              hipStream_t stream) {
    const float* feat1 = (const float*)d_in[0];
    const float* feat2 = (const float*)d_in[1];
    float* out = (float*)d_out;
    const int B = in_sizes[0] / (512 * 16);   // 4096
    corr_kernel<<<dim3(B), dim3(512), 0, stream>>>(feat1, feat2, out);
}